// Round 1
// baseline (154.568 us; speedup 1.0000x reference)
//
#include <hip/hip_runtime.h>
#include <hip/hip_bf16.h>

#define N_ 256
#define S_ 128
#define H_ 512
#define E_ 256
#define O_ 32000
#define KZ 1792   // z row: 1024 ctx + 256 emb + 512 h
#define GJ 2048

typedef __attribute__((ext_vector_type(8))) short sv8;
typedef __attribute__((ext_vector_type(4))) float fv4;

__device__ __forceinline__ unsigned short f2bf(float f) {
  return __builtin_bit_cast(unsigned short, __float2bfloat16(f));
}

__device__ __forceinline__ sv8 pack8(fv4 a, fv4 b) {
  sv8 r;
  r[0] = (short)f2bf(a[0]); r[1] = (short)f2bf(a[1]);
  r[2] = (short)f2bf(a[2]); r[3] = (short)f2bf(a[3]);
  r[4] = (short)f2bf(b[0]); r[5] = (short)f2bf(b[1]);
  r[6] = (short)f2bf(b[2]); r[7] = (short)f2bf(b[3]);
  return r;
}

// ---------------- K1: fused attention + context + embed + h-copy -> z (bf16 [256][1792])
__global__ __launch_bounds__(512) void k_attn(
    const int* __restrict__ x, const float* __restrict__ eo,
    const float* __restrict__ hid, const float* __restrict__ emb,
    const float* __restrict__ We, const float* __restrict__ be,
    unsigned short* __restrict__ z)
{
  const int n = blockIdx.x;
  const int t = threadIdx.x;
  const int w = t >> 6;
  const int l = t & 63;

  __shared__ float s_red[8];
  __shared__ float s_m[8], s_l[8];
  __shared__ float s_ctx[8][1024];

  // hWe = h[n] . We[0:512] + b_energy
  float hv = hid[(size_t)n * H_ + t] * We[t];
  #pragma unroll
  for (int off = 32; off >= 1; off >>= 1) hv += __shfl_xor(hv, off);
  if (l == 0) s_red[w] = hv;
  __syncthreads();
  float hWe = be[0];
  #pragma unroll
  for (int i = 0; i < 8; ++i) hWe += s_red[i];

  // preload We_eo fragment for this lane (loop invariant): elems 4l+256j
  fv4 we0, we1, we2, we3;
  {
    const fv4* wp = (const fv4*)(We + H_);
    we0 = wp[l]; we1 = wp[l + 64]; we2 = wp[l + 128]; we3 = wp[l + 192];
  }

  // online softmax over this wave's 16 s values; ctx accumulated in regs
  float m = 0.f, lsum = 0.f;
  fv4 c0 = {0,0,0,0}, c1 = {0,0,0,0}, c2 = {0,0,0,0}, c3 = {0,0,0,0};
  const float* eob = eo + ((size_t)n * S_ + w * 16) * 1024;
  for (int i = 0; i < 16; ++i) {
    const fv4* p = (const fv4*)(eob + (size_t)i * 1024);
    fv4 v0 = p[l], v1 = p[l + 64], v2 = p[l + 128], v3 = p[l + 192];
    float d = 0.f;
    #pragma unroll
    for (int c = 0; c < 4; ++c)
      d += v0[c]*we0[c] + v1[c]*we1[c] + v2[c]*we2[c] + v3[c]*we3[c];
    #pragma unroll
    for (int off = 32; off >= 1; off >>= 1) d += __shfl_xor(d, off);
    const float e  = fmaxf(d + hWe, 0.f);
    const float mn = fmaxf(m, e);
    const float sc = __expf(m - mn);
    const float pp = __expf(e - mn);
    lsum = lsum * sc + pp;
    #pragma unroll
    for (int c = 0; c < 4; ++c) {
      c0[c] = c0[c]*sc + pp*v0[c];
      c1[c] = c1[c]*sc + pp*v1[c];
      c2[c] = c2[c]*sc + pp*v2[c];
      c3[c] = c3[c]*sc + pp*v3[c];
    }
    m = mn;
  }
  if (l == 0) { s_m[w] = m; s_l[w] = lsum; }
  {
    fv4* sc_ = (fv4*)s_ctx[w];
    sc_[l] = c0; sc_[l+64] = c1; sc_[l+128] = c2; sc_[l+192] = c3;
  }
  __syncthreads();

  float M = s_m[0];
  #pragma unroll
  for (int i = 1; i < 8; ++i) M = fmaxf(M, s_m[i]);
  float wgt[8]; float L = 0.f;
  #pragma unroll
  for (int i = 0; i < 8; ++i) { wgt[i] = __expf(s_m[i] - M); L += wgt[i] * s_l[i]; }
  const float rL = 1.f / L;

  unsigned short* zr = z + (size_t)n * KZ;
  for (int k = t; k < 1024; k += 512) {
    float acc = 0.f;
    #pragma unroll
    for (int i = 0; i < 8; ++i) acc += wgt[i] * s_ctx[i][k];
    zr[k] = f2bf(acc * rL);
  }
  if (t < 256) zr[1024 + t] = f2bf(emb[(size_t)x[n] * E_ + t]);
  zr[1280 + t] = f2bf(hid[(size_t)n * H_ + t]);
}

// ---------------- K2: gates = z @ [W_ih|W_hh]^T  (MFMA bf16), out fp32 [256][2048]
__global__ __launch_bounds__(256) void k_gates(
    const unsigned short* __restrict__ z, const float* __restrict__ Wih,
    const float* __restrict__ Whh, const float* __restrict__ bih,
    const float* __restrict__ bhh, float* __restrict__ gates)
{
  const int j0 = blockIdx.x * 64;
  const int n0 = blockIdx.y * 64;
  const int t = threadIdx.x;
  const int w = t >> 6, l = t & 63;
  const int lr = l & 15, lg = l >> 4;
  const int jb = j0 + w * 16 + lr;

  fv4 acc[4] = {{0,0,0,0},{0,0,0,0},{0,0,0,0},{0,0,0,0}};
  for (int kk = 0; kk < 56; ++kk) {
    const int kb = kk * 32;
    const float* wr;
    if (kb < 1280) wr = Wih + (size_t)jb * 1280 + kb + 8*lg;
    else           wr = Whh + (size_t)jb * 512 + (kb - 1280) + 8*lg;
    const fv4 wa = *(const fv4*)wr;
    const fv4 wb = *(const fv4*)(wr + 4);
    const sv8 bf = pack8(wa, wb);
    #pragma unroll
    for (int f = 0; f < 4; ++f) {
      const sv8 af = *(const sv8*)(z + (size_t)(n0 + f*16 + lr) * KZ + kb + 8*lg);
      acc[f] = __builtin_amdgcn_mfma_f32_16x16x32_bf16(af, bf, acc[f], 0, 0, 0);
    }
  }
  const float bsum = bih[jb] + bhh[jb];
  #pragma unroll
  for (int f = 0; f < 4; ++f) {
    #pragma unroll
    for (int r = 0; r < 4; ++r)
      gates[(size_t)(n0 + f*16 + lg*4 + r) * GJ + jb] = acc[f][r] + bsum;
  }
}

// ---------------- K3: LSTM cell elementwise; writes h_new/c_new (fp32 out) + h bf16
__global__ __launch_bounds__(256) void k_lstm(
    const float* __restrict__ gates, const float* __restrict__ cell,
    float* __restrict__ hout, float* __restrict__ cout,
    unsigned short* __restrict__ hbf)
{
  const int tid = blockIdx.x * 256 + threadIdx.x;
  const int n = tid >> 9, hh = tid & 511;
  const float* g = gates + (size_t)n * GJ;
  float ig = g[hh], fg = g[512 + hh], gg = g[1024 + hh], og = g[1536 + hh];
  ig = 1.f / (1.f + __expf(-ig));
  fg = 1.f / (1.f + __expf(-fg));
  og = 1.f / (1.f + __expf(-og));
  gg = tanhf(gg);
  const float c = fg * cell[tid] + ig * gg;
  const float h = og * tanhf(c);
  cout[tid] = c;
  hout[tid] = h;
  hbf[tid] = f2bf(h);
}

// ---------------- K4: predictions = h_new @ W_out^T + b_out (MFMA bf16, fp32 acc)
__global__ __launch_bounds__(256) void k_pred(
    const unsigned short* __restrict__ hbf, const float* __restrict__ Wout,
    const float* __restrict__ bout, float* __restrict__ pred)
{
  const int o0 = blockIdx.x * 64;
  const int t = threadIdx.x;
  const int w = t >> 6, l = t & 63;
  const int lr = l & 15, lg = l >> 4;
  const int nw = w * 64;

  fv4 acc[4][4] = {};
  for (int kk = 0; kk < 16; ++kk) {
    const int kb = kk * 32 + 8 * lg;
    sv8 a[4];
    #pragma unroll
    for (int fn = 0; fn < 4; ++fn)
      a[fn] = *(const sv8*)(hbf + (size_t)(nw + fn*16 + lr) * H_ + kb);
    #pragma unroll
    for (int fo = 0; fo < 4; ++fo) {
      const float* wr = Wout + (size_t)(o0 + fo*16 + lr) * H_ + kb;
      const fv4 wa = *(const fv4*)wr;
      const fv4 wb = *(const fv4*)(wr + 4);
      const sv8 bf = pack8(wa, wb);
      #pragma unroll
      for (int fn = 0; fn < 4; ++fn)
        acc[fn][fo] = __builtin_amdgcn_mfma_f32_16x16x32_bf16(a[fn], bf, acc[fn][fo], 0, 0, 0);
    }
  }
  #pragma unroll
  for (int fo = 0; fo < 4; ++fo) {
    const int oo = o0 + fo*16 + lr;
    const float bo = bout[oo];
    #pragma unroll
    for (int fn = 0; fn < 4; ++fn) {
      #pragma unroll
      for (int r = 0; r < 4; ++r)
        pred[(size_t)(nw + fn*16 + lg*4 + r) * O_ + oo] = acc[fn][fo][r] + bo;
    }
  }
}

extern "C" void kernel_launch(void* const* d_in, const int* in_sizes, int n_in,
                              void* d_out, int out_size, void* d_ws, size_t ws_size,
                              hipStream_t stream) {
  const int*   x    = (const int*)  d_in[0];
  const float* eo   = (const float*)d_in[1];
  const float* hid  = (const float*)d_in[2];
  const float* cell = (const float*)d_in[3];
  const float* emb  = (const float*)d_in[4];
  const float* We   = (const float*)d_in[5];
  const float* be   = (const float*)d_in[6];
  const float* Wih  = (const float*)d_in[7];
  const float* Whh  = (const float*)d_in[8];
  const float* bih  = (const float*)d_in[9];
  const float* bhh  = (const float*)d_in[10];
  const float* Wout = (const float*)d_in[11];
  const float* bout = (const float*)d_in[12];

  float* pred = (float*)d_out;
  float* hout = pred + (size_t)N_ * O_;
  float* cout = hout + (size_t)N_ * H_;

  unsigned short* z   = (unsigned short*)d_ws;          // 256*1792*2 B
  unsigned short* hbf = z + (size_t)N_ * KZ;            // 256*512*2 B
  float* gates = (float*)(hbf + (size_t)N_ * H_);       // 256*2048*4 B (offset 16B-aligned)

  k_attn <<<256, 512, 0, stream>>>(x, eo, hid, emb, We, be, z);
  k_gates<<<dim3(32, 4), 256, 0, stream>>>(z, Wih, Whh, bih, bhh, gates);
  k_lstm <<<512, 256, 0, stream>>>(gates, cell, hout, cout, hbf);
  k_pred <<<500, 256, 0, stream>>>(hbf, Wout, bout, pred);
}

// Round 2
// 113.259 us; speedup vs baseline: 1.3647x; 1.3647x over previous
//
#include <hip/hip_runtime.h>
#include <hip/hip_bf16.h>

#define N_ 256
#define S_ 128
#define H_ 512
#define E_ 256
#define O_ 32000
#define KZ 1792   // z row: 1024 ctx + 256 emb + 512 h
#define GJ 2048
#define KSPLIT 4
#define KCHUNK 448  // 14 steps of 32

typedef __attribute__((ext_vector_type(8))) short sv8;
typedef __attribute__((ext_vector_type(4))) float fv4;

__device__ __forceinline__ unsigned short f2bf(float f) {
  return __builtin_bit_cast(unsigned short, __float2bfloat16(f));
}

__device__ __forceinline__ sv8 pack8(fv4 a, fv4 b) {
  sv8 r;
  r[0] = (short)f2bf(a[0]); r[1] = (short)f2bf(a[1]);
  r[2] = (short)f2bf(a[2]); r[3] = (short)f2bf(a[3]);
  r[4] = (short)f2bf(b[0]); r[5] = (short)f2bf(b[1]);
  r[6] = (short)f2bf(b[2]); r[7] = (short)f2bf(b[3]);
  return r;
}

// ---------------- K1: fused attention + context + embed + h-copy -> z (bf16 [256][1792])
__global__ __launch_bounds__(512) void k_attn(
    const int* __restrict__ x, const float* __restrict__ eo,
    const float* __restrict__ hid, const float* __restrict__ emb,
    const float* __restrict__ We, const float* __restrict__ be,
    unsigned short* __restrict__ z)
{
  const int n = blockIdx.x;
  const int t = threadIdx.x;
  const int w = t >> 6;
  const int l = t & 63;

  __shared__ float s_red[8];
  __shared__ float s_m[8], s_l[8];
  __shared__ float s_ctx[8][1024];

  // hWe = h[n] . We[0:512] + b_energy
  float hv = hid[(size_t)n * H_ + t] * We[t];
  #pragma unroll
  for (int off = 32; off >= 1; off >>= 1) hv += __shfl_xor(hv, off);
  if (l == 0) s_red[w] = hv;
  __syncthreads();
  float hWe = be[0];
  #pragma unroll
  for (int i = 0; i < 8; ++i) hWe += s_red[i];

  // preload We_eo fragment for this lane (loop invariant): elems 4l+256j
  fv4 we0, we1, we2, we3;
  {
    const fv4* wp = (const fv4*)(We + H_);
    we0 = wp[l]; we1 = wp[l + 64]; we2 = wp[l + 128]; we3 = wp[l + 192];
  }

  // online softmax over this wave's 16 s values; ctx accumulated in regs
  float m = 0.f, lsum = 0.f;
  fv4 c0 = {0,0,0,0}, c1 = {0,0,0,0}, c2 = {0,0,0,0}, c3 = {0,0,0,0};
  const float* eob = eo + ((size_t)n * S_ + w * 16) * 1024;
  for (int i = 0; i < 16; ++i) {
    const fv4* p = (const fv4*)(eob + (size_t)i * 1024);
    fv4 v0 = p[l], v1 = p[l + 64], v2 = p[l + 128], v3 = p[l + 192];
    float d = 0.f;
    #pragma unroll
    for (int c = 0; c < 4; ++c)
      d += v0[c]*we0[c] + v1[c]*we1[c] + v2[c]*we2[c] + v3[c]*we3[c];
    #pragma unroll
    for (int off = 32; off >= 1; off >>= 1) d += __shfl_xor(d, off);
    const float e  = fmaxf(d + hWe, 0.f);
    const float mn = fmaxf(m, e);
    const float sc = __expf(m - mn);
    const float pp = __expf(e - mn);
    lsum = lsum * sc + pp;
    #pragma unroll
    for (int c = 0; c < 4; ++c) {
      c0[c] = c0[c]*sc + pp*v0[c];
      c1[c] = c1[c]*sc + pp*v1[c];
      c2[c] = c2[c]*sc + pp*v2[c];
      c3[c] = c3[c]*sc + pp*v3[c];
    }
    m = mn;
  }
  if (l == 0) { s_m[w] = m; s_l[w] = lsum; }
  {
    fv4* sc_ = (fv4*)s_ctx[w];
    sc_[l] = c0; sc_[l+64] = c1; sc_[l+128] = c2; sc_[l+192] = c3;
  }
  __syncthreads();

  float M = s_m[0];
  #pragma unroll
  for (int i = 1; i < 8; ++i) M = fmaxf(M, s_m[i]);
  float wgt[8]; float L = 0.f;
  #pragma unroll
  for (int i = 0; i < 8; ++i) { wgt[i] = __expf(s_m[i] - M); L += wgt[i] * s_l[i]; }
  const float rL = 1.f / L;

  unsigned short* zr = z + (size_t)n * KZ;
  for (int k = t; k < 1024; k += 512) {
    float acc = 0.f;
    #pragma unroll
    for (int i = 0; i < 8; ++i) acc += wgt[i] * s_ctx[i][k];
    zr[k] = f2bf(acc * rL);
  }
  if (t < 256) zr[1024 + t] = f2bf(emb[(size_t)x[n] * E_ + t]);
  zr[1280 + t] = f2bf(hid[(size_t)n * H_ + t]);
}

// ---------------- K2: partial gates = z @ [W_ih|W_hh]^T  (MFMA bf16, K-split)
// grid (32 j-tiles, 4 n-tiles, 4 k-chunks); part[k][n][j] fp32
__global__ __launch_bounds__(256) void k_gates(
    const unsigned short* __restrict__ z, const float* __restrict__ Wih,
    const float* __restrict__ Whh, float* __restrict__ part)
{
  const int j0 = blockIdx.x * 64;
  const int n0 = blockIdx.y * 64;
  const int kc = blockIdx.z * KCHUNK;
  const int t = threadIdx.x;
  const int w = t >> 6, l = t & 63;
  const int lr = l & 15, lg = l >> 4;
  const int jb = j0 + w * 16 + lr;

  const unsigned short* arow = z + kc + 8 * lg;

  fv4 acc[4] = {{0,0,0,0},{0,0,0,0},{0,0,0,0},{0,0,0,0}};
  #pragma unroll
  for (int s = 0; s < 14; ++s) {
    const int kb = kc + s * 32;
    const float* wr;
    if (kb < 1280) wr = Wih + (size_t)jb * 1280 + kb + 8*lg;
    else           wr = Whh + (size_t)jb * 512 + (kb - 1280) + 8*lg;
    const fv4 wa = *(const fv4*)wr;
    const fv4 wb = *(const fv4*)(wr + 4);
    const sv8 bf = pack8(wa, wb);
    #pragma unroll
    for (int f = 0; f < 4; ++f) {
      const sv8 af = *(const sv8*)(arow + (size_t)(n0 + f*16 + lr) * KZ + s * 32);
      acc[f] = __builtin_amdgcn_mfma_f32_16x16x32_bf16(af, bf, acc[f], 0, 0, 0);
    }
  }
  float* pp = part + (size_t)blockIdx.z * (N_ * GJ);
  #pragma unroll
  for (int f = 0; f < 4; ++f) {
    #pragma unroll
    for (int r = 0; r < 4; ++r)
      pp[(size_t)(n0 + f*16 + lg*4 + r) * GJ + jb] = acc[f][r];
  }
}

// ---------------- K3: LSTM cell elementwise; reduces K-split partials + biases
__global__ __launch_bounds__(256) void k_lstm(
    const float* __restrict__ part, const float* __restrict__ cell,
    const float* __restrict__ bih, const float* __restrict__ bhh,
    float* __restrict__ hout, float* __restrict__ cout,
    unsigned short* __restrict__ hbf)
{
  const int tid = blockIdx.x * 256 + threadIdx.x;
  const int n = tid >> 9, hh = tid & 511;
  const size_t base = (size_t)n * GJ;
  float ig = bih[hh]        + bhh[hh];
  float fg = bih[512 + hh]  + bhh[512 + hh];
  float gg = bih[1024 + hh] + bhh[1024 + hh];
  float og = bih[1536 + hh] + bhh[1536 + hh];
  #pragma unroll
  for (int k = 0; k < KSPLIT; ++k) {
    const float* p = part + (size_t)k * (N_ * GJ) + base;
    ig += p[hh];
    fg += p[512 + hh];
    gg += p[1024 + hh];
    og += p[1536 + hh];
  }
  ig = 1.f / (1.f + __expf(-ig));
  fg = 1.f / (1.f + __expf(-fg));
  og = 1.f / (1.f + __expf(-og));
  gg = tanhf(gg);
  const float c = fg * cell[tid] + ig * gg;
  const float h = og * tanhf(c);
  cout[tid] = c;
  hout[tid] = h;
  hbf[tid] = f2bf(h);
}

// ---------------- K4: predictions = h_new @ W_out^T + b_out (MFMA bf16, fp32 acc)
__global__ __launch_bounds__(256) void k_pred(
    const unsigned short* __restrict__ hbf, const float* __restrict__ Wout,
    const float* __restrict__ bout, float* __restrict__ pred)
{
  const int o0 = blockIdx.x * 64;
  const int t = threadIdx.x;
  const int w = t >> 6, l = t & 63;
  const int lr = l & 15, lg = l >> 4;
  const int nw = w * 64;

  fv4 acc[4][4] = {};
  for (int kk = 0; kk < 16; ++kk) {
    const int kb = kk * 32 + 8 * lg;
    sv8 a[4];
    #pragma unroll
    for (int fn = 0; fn < 4; ++fn)
      a[fn] = *(const sv8*)(hbf + (size_t)(nw + fn*16 + lr) * H_ + kb);
    #pragma unroll
    for (int fo = 0; fo < 4; ++fo) {
      const float* wr = Wout + (size_t)(o0 + fo*16 + lr) * H_ + kb;
      const fv4 wa = *(const fv4*)wr;
      const fv4 wb = *(const fv4*)(wr + 4);
      const sv8 bf = pack8(wa, wb);
      #pragma unroll
      for (int fn = 0; fn < 4; ++fn)
        acc[fn][fo] = __builtin_amdgcn_mfma_f32_16x16x32_bf16(a[fn], bf, acc[fn][fo], 0, 0, 0);
    }
  }
  #pragma unroll
  for (int fo = 0; fo < 4; ++fo) {
    const int oo = o0 + fo*16 + lr;
    const float bo = bout[oo];
    #pragma unroll
    for (int fn = 0; fn < 4; ++fn) {
      #pragma unroll
      for (int r = 0; r < 4; ++r)
        pred[(size_t)(nw + fn*16 + lg*4 + r) * O_ + oo] = acc[fn][fo][r] + bo;
    }
  }
}

extern "C" void kernel_launch(void* const* d_in, const int* in_sizes, int n_in,
                              void* d_out, int out_size, void* d_ws, size_t ws_size,
                              hipStream_t stream) {
  const int*   x    = (const int*)  d_in[0];
  const float* eo   = (const float*)d_in[1];
  const float* hid  = (const float*)d_in[2];
  const float* cell = (const float*)d_in[3];
  const float* emb  = (const float*)d_in[4];
  const float* We   = (const float*)d_in[5];
  const float* be   = (const float*)d_in[6];
  const float* Wih  = (const float*)d_in[7];
  const float* Whh  = (const float*)d_in[8];
  const float* bih  = (const float*)d_in[9];
  const float* bhh  = (const float*)d_in[10];
  const float* Wout = (const float*)d_in[11];
  const float* bout = (const float*)d_in[12];

  float* pred = (float*)d_out;
  float* hout = pred + (size_t)N_ * O_;
  float* cout = hout + (size_t)N_ * H_;

  unsigned short* z   = (unsigned short*)d_ws;          // 256*1792*2 B = 917504
  unsigned short* hbf = z + (size_t)N_ * KZ;            // 256*512*2 B  = 262144
  float* part = (float*)(hbf + (size_t)N_ * H_);        // 4*256*2048*4 B = 8 MB

  k_attn <<<256, 512, 0, stream>>>(x, eo, hid, emb, We, be, z);
  k_gates<<<dim3(32, 4, KSPLIT), 256, 0, stream>>>(z, Wih, Whh, part);
  k_lstm <<<512, 256, 0, stream>>>(part, cell, bih, bhh, hout, cout, hbf);
  k_pred <<<500, 256, 0, stream>>>(hbf, Wout, bout, pred);
}